// Round 14
// baseline (172.869 us; speedup 1.0000x reference)
//
#include <hip/hip_runtime.h>
#include <hip/hip_bf16.h>
#include <cstdint>
#include <cstddef>

typedef __bf16 bf16x8 __attribute__((ext_vector_type(8)));
typedef __bf16 bf16x4 __attribute__((ext_vector_type(4)));
typedef __bf16 bf16x2 __attribute__((ext_vector_type(2)));
typedef float  f32x4  __attribute__((ext_vector_type(4)));
typedef float  f32x2  __attribute__((ext_vector_type(2)));

#define T_SEQ 2048
#define CDIM  2048
#define NH    16
#define NG    4
#define DH    128
#define NCHUNK 32   // T / 64

__device__ __forceinline__ void gl_lds16(const __bf16* g, __bf16* l) {
  __builtin_amdgcn_global_load_lds(
      (const __attribute__((address_space(1))) void*)g,
      (__attribute__((address_space(3))) void*)l, 16, 0, 0);
}

// ---------------- fused preprocess: cast x->bf16, transpose+cast 3 weights ----------------
__global__ __launch_bounds__(256) void pre_kernel(
    const float* __restrict__ x, const float* __restrict__ Wr,
    const float* __restrict__ Wg, const float* __restrict__ Wp,
    __bf16* __restrict__ xb, __bf16* __restrict__ wtb, __bf16* __restrict__ wpb) {
  __shared__ __bf16 tile[64][68];
  int bid = blockIdx.x;
  int tid = threadIdx.x;
  if (bid < 2048) {   // cast x (4M elements)
    size_t i = ((size_t)bid * 256 + tid) * 8;
    f32x4 a = *(const f32x4*)(x + i);
    f32x4 b = *(const f32x4*)(x + i + 4);
    bf16x8 o;
#pragma unroll
    for (int j = 0; j < 4; ++j) { o[j] = (__bf16)a[j]; o[4 + j] = (__bf16)b[j]; }
    *(bf16x8*)(xb + i) = o;
    return;
  }
  int rel = bid - 2048;
  const float* W; __bf16* Wt; int N;
  if (rel < 1536)      { W = Wr; Wt = wtb;                        N = 3072; }
  else if (rel < 2560) { W = Wg; Wt = wtb + (size_t)3072 * CDIM;  N = 2048; rel -= 1536; }
  else                 { W = Wp; Wt = wpb;                        N = 2048; rel -= 2560; }
  const int K = 2048;
  int k0 = (rel & 31) * 64, n0 = (rel >> 5) * 64;
  int c4 = (tid & 15) * 4, r = tid >> 4;
#pragma unroll
  for (int rr = 0; rr < 4; ++rr) {
    int row = r + rr * 16;
    f32x4 v = *(const f32x4*)(W + (size_t)(k0 + row) * N + n0 + c4);
#pragma unroll
    for (int j = 0; j < 4; ++j) tile[row][c4 + j] = (__bf16)v[j];
  }
  __syncthreads();
  int n = tid >> 2, seg = tid & 3;
  __bf16 vals[16];
#pragma unroll
  for (int j = 0; j < 16; ++j) vals[j] = tile[seg * 16 + j][n];
  __bf16* dst = Wt + (size_t)(n0 + n) * K + k0 + seg * 16;
  *(bf16x8*)(dst)     = *(bf16x8*)(&vals[0]);
  *(bf16x8*)(dst + 8) = *(bf16x8*)(&vals[8]);
}

// ---------------- fused U+scan: per (h, d2-slice, d1-half) block, sequential over chunks ----
__global__ __launch_bounds__(256) void uscan_kernel(const __bf16* __restrict__ vtb,
                                                    const __bf16* __restrict__ ktb,
                                                    __bf16* __restrict__ St) {
  int bid = blockIdx.x;                 // NH*8*2 = 256
  int h = bid >> 4, m = (bid >> 1) & 7, half = bid & 1;
  int g = h >> 2;
  int tid = threadIdx.x, w = tid >> 6, l = tid & 63, lr = l & 15, lg = l >> 4;
  int jf = half * 4 + w;                // d1 block 0..7
  float l2g = log2f(1.0f - exp2f(-5.0f - (float)h));
  float ginv = exp2f(-l2g);             // 1/gamma
  float df   = exp2f(l2g * 64.0f);      // gamma^64
  float wk[2];
#pragma unroll
  for (int kk = 0; kk < 2; ++kk) wk[kk] = exp2f(l2g * (float)(64 - (kk * 32 + lg * 8)));
  const __bf16* vrow = vtb + ((size_t)g * DH + m * 16 + lr) * T_SEQ;
  const __bf16* krow = ktb + ((size_t)g * DH + jf * 16 + lr) * T_SEQ;
  f32x4 S = {0.f, 0.f, 0.f, 0.f};
  for (int c = 0; c < NCHUNK; ++c) {
    f32x4 u = {0.f, 0.f, 0.f, 0.f};
#pragma unroll
    for (int kk = 0; kk < 2; ++kk) {
      int j0 = c * 64 + kk * 32 + lg * 8;
      bf16x8 av = *(const bf16x8*)(vrow + j0);
      bf16x8 bv = *(const bf16x8*)(krow + j0);
      bf16x8 aw;
      float wj = wk[kk];
#pragma unroll
      for (int jj = 0; jj < 8; ++jj) { aw[jj] = (__bf16)((float)av[jj] * wj); wj *= ginv; }
      u = __builtin_amdgcn_mfma_f32_16x16x32_bf16(aw, bv, u, 0, 0, 0);
    }
    __bf16* out = St + ((size_t)(h * NCHUNK + c) * 128 + m * 16 + lg * 4) * 128 + jf * 16 + lr;
#pragma unroll
    for (int r = 0; r < 4; ++r) out[r * 128] = (__bf16)S[r];
#pragma unroll
    for (int r = 0; r < 4; ++r) S[r] = df * S[r] + u[r];
  }
}

// ---- stage-3 attention + fused RMS-norm + gate ----
__global__ __launch_bounds__(256) void attn2_kernel(const __bf16* __restrict__ qb,
    const __bf16* __restrict__ kb, const __bf16* __restrict__ vtb,
    const __bf16* __restrict__ St, const __bf16* __restrict__ gateb,
    __bf16* __restrict__ ynormb) {
  __shared__ __bf16 kl[64 * 128];
  __shared__ __bf16 vl[128 * 64];
  __shared__ __bf16 pl[4][16 * 64];
  int h = blockIdx.x >> 5, qt = blockIdx.x & 31;
  int g = h >> 2;
  int w = threadIdx.x >> 6, l = threadIdx.x & 63;
  int lr = l & 15, lg = l >> 4;
  int t0b = qt * 64;
  int t0 = t0b + w * 16;
  bf16x8 qf[4];
#pragma unroll
  for (int kbk = 0; kbk < 4; ++kbk)
    qf[kbk] = *(const bf16x8*)(qb + ((size_t)h * T_SEQ + t0 + lr) * DH + kbk * 32 + lg * 8);
  float gamma = 1.0f - exp2f(-5.0f - (float)h);
  float l2g = log2f(gamma);
  const float scale = 0.088388347648318447f;  // 1/sqrt(128)
  int s0 = t0b;
#pragma unroll
  for (int it = 0; it < 4; ++it) {
    int fg = it * 256 + threadIdx.x;
    {
      int ss = fg >> 4, gr = fg & 15;
      bf16x8 kv = *(const bf16x8*)(kb + ((size_t)g * T_SEQ + s0 + ss) * DH + gr * 8);
      *(bf16x8*)((char*)kl + ss * 256 + ((gr * 16) ^ ((ss & 7) << 4))) = kv;
    }
    {
      int d = fg >> 3, gv = fg & 7;
      bf16x8 vv = *(const bf16x8*)(vtb + ((size_t)g * DH + d) * T_SEQ + s0 + gv * 8);
      *(bf16x8*)((char*)vl + d * 128 + ((gv * 16) ^ ((d & 7) << 4))) = vv;
    }
  }
  float wfac = scale * exp2f(l2g * (float)(w * 16 + lr));
  bf16x8 qwf[4];
#pragma unroll
  for (int kbk = 0; kbk < 4; ++kbk)
#pragma unroll
    for (int e = 0; e < 8; ++e) qwf[kbk][e] = (__bf16)((float)qf[kbk][e] * wfac);
  f32x4 acc[8] = {};
  const __bf16* Sb = St + (size_t)(h * NCHUNK + qt) * 16384;
#pragma unroll
  for (int dc = 0; dc < 8; ++dc)
#pragma unroll
    for (int kc = 0; kc < 4; ++kc) {
      bf16x8 sf = *(const bf16x8*)(Sb + (dc * 16 + lr) * 128 + kc * 32 + lg * 8);
      acc[dc] = __builtin_amdgcn_mfma_f32_16x16x32_bf16(qwf[kc], sf, acc[dc], 0, 0, 0);
    }
  __syncthreads();
#pragma unroll
  for (int sc = 0; sc < 4; ++sc) {
    f32x4 p = {0.f, 0.f, 0.f, 0.f};
    int srow = sc * 16 + lr;
#pragma unroll
    for (int kbk = 0; kbk < 4; ++kbk) {
      bf16x8 kf = *(const bf16x8*)((char*)kl + srow * 256 +
                                   ((kbk * 64 + lg * 16) ^ ((srow & 7) << 4)));
      p = __builtin_amdgcn_mfma_f32_16x16x32_bf16(qf[kbk], kf, p, 0, 0, 0);
    }
#pragma unroll
    for (int r = 0; r < 4; ++r) {
      int tl = lg * 4 + r;
      int diff = (w * 16 + tl) - srow;
      float val = 0.0f;
      if (diff >= 0) val = p[r] * scale * exp2f((float)diff * l2g);
      *(__bf16*)((char*)(pl[w]) + tl * 128 +
                 (((sc * 16 + lr) * 2) ^ ((tl & 7) << 4))) = (__bf16)val;
    }
  }
  bf16x8 pa[2];
#pragma unroll
  for (int kc = 0; kc < 2; ++kc)
    pa[kc] = *(const bf16x8*)((char*)(pl[w]) + lr * 128 +
                              ((kc * 64 + lg * 16) ^ ((lr & 7) << 4)));
#pragma unroll
  for (int dc = 0; dc < 8; ++dc) {
#pragma unroll
    for (int kc = 0; kc < 2; ++kc) {
      int vrow = dc * 16 + lr;
      bf16x8 vf = *(const bf16x8*)((char*)vl + vrow * 128 +
                                   ((kc * 64 + lg * 16) ^ ((vrow & 7) << 4)));
      acc[dc] = __builtin_amdgcn_mfma_f32_16x16x32_bf16(pa[kc], vf, acc[dc], 0, 0, 0);
    }
  }
  float rs[4];
#pragma unroll
  for (int r = 0; r < 4; ++r) {
    float ssum = 0.f;
#pragma unroll
    for (int dc = 0; dc < 8; ++dc) ssum += acc[dc][r] * acc[dc][r];
    ssum += __shfl_xor(ssum, 1, 64);
    ssum += __shfl_xor(ssum, 2, 64);
    ssum += __shfl_xor(ssum, 4, 64);
    ssum += __shfl_xor(ssum, 8, 64);
    rs[r] = rsqrtf(ssum * (1.0f / 128.0f) + 1e-5f);
  }
#pragma unroll
  for (int dc = 0; dc < 8; ++dc)
#pragma unroll
    for (int r = 0; r < 4; ++r) {
      size_t idx = (size_t)(t0 + lg * 4 + r) * CDIM + h * DH + dc * 16 + lr;
      float gv = (float)gateb[idx];
      ynormb[idx] = (__bf16)(acc[dc][r] * rs[r] * gv);
    }
}

// ------- GEMM: BMx128 tile (MI = BM/32 M-frags/wave), BK=64, depth-2 counted-vmcnt -------
// Schedule per K-step: compute(cur) -> s_barrier -> stage(cur, kt+2) -> vmcnt(MI+4) -> barrier.
// Per-wave loads per stage = MI (A) + 4 (B); counted wait keeps next tile's loads in flight.
// MODE 0: Cf[row*N+col] = z (f32).
// MODE 1: fused epilogue -- n0<3072: RoPE q,k in-register and scatter to qb/kb/ktb, v->vtb;
//   n0>=3072: silu(z) -> gateb.
template<int MODE, int MI>
__global__ __launch_bounds__(256) void gemm_gl_kernel(
    const __bf16* __restrict__ A, const __bf16* __restrict__ Bt,
    float* __restrict__ Cf, __bf16* __restrict__ Cg,
    const float* __restrict__ cosb, const float* __restrict__ sinb,
    __bf16* __restrict__ qb, __bf16* __restrict__ kb,
    __bf16* __restrict__ vtb, __bf16* __restrict__ ktb,
    int M, int N, int K) {
  constexpr int BM = MI * 32;                    // 64 or 128
  __shared__ __bf16 Asb[2 * BM * 64];            // 2 x BM*128B buffers
  __shared__ __bf16 Bsb[2 * 128 * 64];           // 2 x 16KB buffers
  int m0 = blockIdx.x * BM, n0 = blockIdx.y * 128;
  int tid = threadIdx.x;
  int w = tid >> 6, l = tid & 63;
  int wr = w >> 1, wc = w & 1;                   // wave tile = (16*MI) x 64
  int lr = l & 15, lg = l >> 4;
  int nk = K >> 6;
  const __bf16* Ab = A + (size_t)m0 * K;
  const __bf16* Bb = Bt + (size_t)n0 * K;
  f32x4 acc[MI][4] = {};

  auto stage = [&](int buf, int k0) {
#pragma unroll
    for (int c = 0; c < MI; ++c) {
      int ca = c * 256 + tid, row = ca >> 3, ks = ca & 7;
      gl_lds16(Ab + (size_t)row * K + k0 + ((ks ^ (row & 7)) << 3),
               Asb + buf * (BM * 64) + ca * 8);
    }
#pragma unroll
    for (int c = 0; c < 4; ++c) {
      int cb2 = c * 256 + tid, row = cb2 >> 3, ks = cb2 & 7;
      gl_lds16(Bb + (size_t)row * K + k0 + ((ks ^ (row & 7)) << 3),
               Bsb + buf * 8192 + cb2 * 8);
    }
  };
  auto wait_tile = [] {                          // vmcnt(MI+4): one tile's loads outstanding
    if constexpr (MI == 2) asm volatile("s_waitcnt vmcnt(6)" ::: "memory");
    else                   asm volatile("s_waitcnt vmcnt(8)" ::: "memory");
  };

  // prologue: stage tiles 0 and 1; wait only for tile 0
  stage(0, 0);
  if (nk > 1) {
    stage(1, 64);
    wait_tile();
  } else {
    asm volatile("s_waitcnt vmcnt(0)" ::: "memory");
  }
  __builtin_amdgcn_s_barrier();

  int cur = 0;
  for (int kt = 0; kt < nk; ++kt) {
    const char* As = (const char*)(Asb + cur * (BM * 64));
    const char* Bs = (const char*)(Bsb + cur * 8192);
    bf16x8 av[MI][2], bv[4][2];
#pragma unroll
    for (int i = 0; i < MI; ++i)
#pragma unroll
      for (int kk = 0; kk < 2; ++kk) {
        int row = wr * (16 * MI) + i * 16 + lr;
        av[i][kk] = *(const bf16x8*)(As +
            ((row * 128 + kk * 64 + lg * 16) ^ ((lr & 7) << 4)));
      }
#pragma unroll
    for (int j = 0; j < 4; ++j)
#pragma unroll
      for (int kk = 0; kk < 2; ++kk) {
        int row = wc * 64 + j * 16 + lr;
        bv[j][kk] = *(const bf16x8*)(Bs +
            ((row * 128 + kk * 64 + lg * 16) ^ ((lr & 7) << 4)));
      }
#pragma unroll
    for (int kk = 0; kk < 2; ++kk)
#pragma unroll
      for (int i = 0; i < MI; ++i)
#pragma unroll
        for (int j = 0; j < 4; ++j)
          acc[i][j] = __builtin_amdgcn_mfma_f32_16x16x32_bf16(av[i][kk], bv[j][kk],
                                                              acc[i][j], 0, 0, 0);
    if (kt + 1 < nk) {
      __builtin_amdgcn_s_barrier();        // all waves finished reading buf cur
      if (kt + 2 < nk) {
        stage(cur, (kt + 2) << 6);         // refill buf cur; stays in flight next phase
        wait_tile();                       // tile kt+1 (oldest) landed
      } else {
        asm volatile("s_waitcnt vmcnt(0)" ::: "memory");   // tail: tile kt+1 landed
      }
      __builtin_amdgcn_s_barrier();
    }
    cur ^= 1;
  }

  if (MODE == 0) {
#pragma unroll
    for (int i = 0; i < MI; ++i) {
      int row = m0 + wr * (16 * MI) + i * 16 + lg * 4;
#pragma unroll
      for (int j = 0; j < 4; ++j) {
        int col = n0 + wc * 64 + j * 16 + lr;
#pragma unroll
        for (int r = 0; r < 4; ++r)
          Cf[(size_t)(row + r) * N + col] = acc[i][j][r];
      }
    }
    return;
  }
  // MODE 1 fused epilogue
  if (n0 >= 3072) {
#pragma unroll
    for (int i = 0; i < MI; ++i) {
      int row = m0 + wr * (16 * MI) + i * 16 + lg * 4;
#pragma unroll
      for (int j = 0; j < 4; ++j) {
        int col = n0 + wc * 64 + j * 16 + lr;
#pragma unroll
        for (int r = 0; r < 4; ++r) {
          float z = acc[i][j][r];
          float sv = z / (1.0f + expf(-z));
          Cg[(size_t)(row + r) * 2048 + (col - 3072)] = (__bf16)sv;
        }
      }
    }
    return;
  }
  // qkv section: rope q,k in-register and scatter; v -> vtb
#pragma unroll
  for (int i = 0; i < MI; ++i) {
    int row0 = m0 + wr * (16 * MI) + i * 16 + lg * 4;
#pragma unroll
    for (int j = 0; j < 4; ++j) {
      int cb = n0 + wc * 64 + j * 16;            // frag base col (wave-uniform)
      int g = cb / 768, cm = cb % 768;
      int dbase = (cm < 512) ? (cm & 127) : (cm < 640) ? (cm - 512) : (cm - 640);
      int d = dbase + lr;
      float ov[4];
      if (cm < 640) {                            // rope (q or k)
#pragma unroll
        for (int r = 0; r < 4; ++r) {
          float z = acc[i][j][r];
          float pz = __shfl_xor(z, 1, 64);       // pair partner (col parity == lr parity)
          int t = row0 + r;
          float cc = cosb[t * 64 + (d >> 1)];
          float ss = sinb[t * 64 + (d >> 1)];
          ov[r] = (lr & 1) ? (pz * ss + z * cc) : (z * cc - pz * ss);
        }
      } else {
#pragma unroll
        for (int r = 0; r < 4; ++r) ov[r] = acc[i][j][r];
      }
      if (cm < 512) {                            // q -> qb[h][t][d]
        int hh = g * 4 + (cm >> 7);
#pragma unroll
        for (int r = 0; r < 4; ++r)
          qb[((size_t)hh * T_SEQ + row0 + r) * DH + d] = (__bf16)ov[r];
      } else if (cm < 640) {                     // k -> kb[g][t][d] and ktb[g][d][t]
        bf16x4 kv;
#pragma unroll
        for (int r = 0; r < 4; ++r) {
          kv[r] = (__bf16)ov[r];
          kb[((size_t)g * T_SEQ + row0 + r) * DH + d] = kv[r];
        }
        *(bf16x4*)(ktb + ((size_t)g * DH + d) * T_SEQ + row0) = kv;
      } else {                                   // v -> vtb[g][d][t]
        bf16x4 vv;
#pragma unroll
        for (int r = 0; r < 4; ++r) vv[r] = (__bf16)ov[r];
        *(bf16x4*)(vtb + ((size_t)g * DH + d) * T_SEQ + row0) = vv;
      }
    }
  }
}

extern "C" void kernel_launch(void* const* d_in, const int* in_sizes, int n_in,
                              void* d_out, int out_size, void* d_ws, size_t ws_size,
                              hipStream_t stream) {
  const float* x    = (const float*)d_in[0];
  const float* cosb = (const float*)d_in[1];
  const float* sinb = (const float*)d_in[2];
  // d_in[3] = mask (268MB) -- computed analytically, never read
  const float* Wr   = (const float*)d_in[4];
  const float* Wg   = (const float*)d_in[5];
  const float* Wp   = (const float*)d_in[6];

  char* ws = (char*)d_ws;
  size_t off = 0;
  auto alloc = [&](size_t bytes) { void* p = ws + off; off += (bytes + 255) & ~(size_t)255; return p; };
  __bf16* xb     = (__bf16*)alloc((size_t)CDIM * CDIM * 2);          // 8MB
  __bf16* wtb    = (__bf16*)alloc((size_t)5120 * CDIM * 2);          // 20MB (W_reten^T|W_gate^T)
  __bf16* wpb    = (__bf16*)alloc((size_t)CDIM * CDIM * 2);          // 8MB
  __bf16* qb     = (__bf16*)alloc((size_t)NH * T_SEQ * DH * 2);      // 8MB
  __bf16* kbp    = (__bf16*)alloc((size_t)NG * T_SEQ * DH * 2);      // 2MB
  __bf16* vtb    = (__bf16*)alloc((size_t)NG * DH * T_SEQ * 2);      // 2MB
  __bf16* ktb    = (__bf16*)alloc((size_t)NG * DH * T_SEQ * 2);      // 2MB
  __bf16* gateb  = (__bf16*)alloc((size_t)CDIM * CDIM * 2);          // 8MB
  __bf16* Stb    = (__bf16*)alloc((size_t)NH * NCHUNK * 128 * 128 * 2); // 16MB
  __bf16* ynormb = (__bf16*)alloc((size_t)T_SEQ * CDIM * 2);         // 8MB

  // 1) preprocess: cast x + transpose/cast all weights
  pre_kernel<<<5632, 256, 0, stream>>>(x, Wr, Wg, Wp, xb, wtb, wpb);
  // 2) fused: x @ [W_reten | W_gate] with in-epilogue RoPE/scatter/transpose + silu gate
  //    128x128 tile (MI=4): better load:MFMA and ds_read:MFMA ratios; grid 640 = 2.5/CU.
  gemm_gl_kernel<1, 4><<<dim3(16, 40), 256, 0, stream>>>(
      xb, wtb, nullptr, gateb, cosb, sinb, qb, kbp, vtb, ktb, 2048, 5120, 2048);
  // 3) fused per-chunk decayed KV outer products + state scan -> St bf16
  uscan_kernel<<<256, 256, 0, stream>>>(vtb, ktb, Stb);
  // 4) attention (intra tile + q@S_c) + fused RMS-norm + gate -> ynorm bf16 [T][C]
  attn2_kernel<<<NH * NCHUNK, 256, 0, stream>>>(qb, kbp, vtb, Stb, gateb, ynormb);
  // 5) out = (g*y_norm) @ W_proj -- 64x128 (MI=2) kept: 512 blocks = 2/CU (proven R10 config)
  gemm_gl_kernel<0, 2><<<dim3(32, 16), 256, 0, stream>>>(
      ynormb, wpb, (float*)d_out, nullptr, nullptr, nullptr, nullptr, nullptr, nullptr, nullptr,
      2048, 2048, 2048);
}

// Round 15
// 157.059 us; speedup vs baseline: 1.1007x; 1.1007x over previous
//
#include <hip/hip_runtime.h>
#include <hip/hip_bf16.h>
#include <cstdint>
#include <cstddef>

typedef __bf16 bf16x8 __attribute__((ext_vector_type(8)));
typedef __bf16 bf16x4 __attribute__((ext_vector_type(4)));
typedef __bf16 bf16x2 __attribute__((ext_vector_type(2)));
typedef float  f32x4  __attribute__((ext_vector_type(4)));
typedef float  f32x2  __attribute__((ext_vector_type(2)));

#define T_SEQ 2048
#define CDIM  2048
#define NH    16
#define NG    4
#define DH    128
#define NCHUNK 32   // T / 64

__device__ __forceinline__ void gl_lds16(const __bf16* g, __bf16* l) {
  __builtin_amdgcn_global_load_lds(
      (const __attribute__((address_space(1))) void*)g,
      (__attribute__((address_space(3))) void*)l, 16, 0, 0);
}

// ---------------- fused preprocess: cast x->bf16, transpose+cast 3 weights ----------------
__global__ __launch_bounds__(256) void pre_kernel(
    const float* __restrict__ x, const float* __restrict__ Wr,
    const float* __restrict__ Wg, const float* __restrict__ Wp,
    __bf16* __restrict__ xb, __bf16* __restrict__ wtb, __bf16* __restrict__ wpb) {
  __shared__ __bf16 tile[64][68];
  int bid = blockIdx.x;
  int tid = threadIdx.x;
  if (bid < 2048) {   // cast x (4M elements)
    size_t i = ((size_t)bid * 256 + tid) * 8;
    f32x4 a = *(const f32x4*)(x + i);
    f32x4 b = *(const f32x4*)(x + i + 4);
    bf16x8 o;
#pragma unroll
    for (int j = 0; j < 4; ++j) { o[j] = (__bf16)a[j]; o[4 + j] = (__bf16)b[j]; }
    *(bf16x8*)(xb + i) = o;
    return;
  }
  int rel = bid - 2048;
  const float* W; __bf16* Wt; int N;
  if (rel < 1536)      { W = Wr; Wt = wtb;                        N = 3072; }
  else if (rel < 2560) { W = Wg; Wt = wtb + (size_t)3072 * CDIM;  N = 2048; rel -= 1536; }
  else                 { W = Wp; Wt = wpb;                        N = 2048; rel -= 2560; }
  const int K = 2048;
  int k0 = (rel & 31) * 64, n0 = (rel >> 5) * 64;
  int c4 = (tid & 15) * 4, r = tid >> 4;
#pragma unroll
  for (int rr = 0; rr < 4; ++rr) {
    int row = r + rr * 16;
    f32x4 v = *(const f32x4*)(W + (size_t)(k0 + row) * N + n0 + c4);
#pragma unroll
    for (int j = 0; j < 4; ++j) tile[row][c4 + j] = (__bf16)v[j];
  }
  __syncthreads();
  int n = tid >> 2, seg = tid & 3;
  __bf16 vals[16];
#pragma unroll
  for (int j = 0; j < 16; ++j) vals[j] = tile[seg * 16 + j][n];
  __bf16* dst = Wt + (size_t)(n0 + n) * K + k0 + seg * 16;
  *(bf16x8*)(dst)     = *(bf16x8*)(&vals[0]);
  *(bf16x8*)(dst + 8) = *(bf16x8*)(&vals[8]);
}

// ---------------- fused U+scan: per (h, d2-slice, d1-half) block, sequential over chunks ----
__global__ __launch_bounds__(256) void uscan_kernel(const __bf16* __restrict__ vtb,
                                                    const __bf16* __restrict__ ktb,
                                                    __bf16* __restrict__ St) {
  int bid = blockIdx.x;                 // NH*8*2 = 256
  int h = bid >> 4, m = (bid >> 1) & 7, half = bid & 1;
  int g = h >> 2;
  int tid = threadIdx.x, w = tid >> 6, l = tid & 63, lr = l & 15, lg = l >> 4;
  int jf = half * 4 + w;                // d1 block 0..7
  float l2g = log2f(1.0f - exp2f(-5.0f - (float)h));
  float ginv = exp2f(-l2g);             // 1/gamma
  float df   = exp2f(l2g * 64.0f);      // gamma^64
  float wk[2];
#pragma unroll
  for (int kk = 0; kk < 2; ++kk) wk[kk] = exp2f(l2g * (float)(64 - (kk * 32 + lg * 8)));
  const __bf16* vrow = vtb + ((size_t)g * DH + m * 16 + lr) * T_SEQ;
  const __bf16* krow = ktb + ((size_t)g * DH + jf * 16 + lr) * T_SEQ;
  f32x4 S = {0.f, 0.f, 0.f, 0.f};
  for (int c = 0; c < NCHUNK; ++c) {
    f32x4 u = {0.f, 0.f, 0.f, 0.f};
#pragma unroll
    for (int kk = 0; kk < 2; ++kk) {
      int j0 = c * 64 + kk * 32 + lg * 8;
      bf16x8 av = *(const bf16x8*)(vrow + j0);
      bf16x8 bv = *(const bf16x8*)(krow + j0);
      bf16x8 aw;
      float wj = wk[kk];
#pragma unroll
      for (int jj = 0; jj < 8; ++jj) { aw[jj] = (__bf16)((float)av[jj] * wj); wj *= ginv; }
      u = __builtin_amdgcn_mfma_f32_16x16x32_bf16(aw, bv, u, 0, 0, 0);
    }
    __bf16* out = St + ((size_t)(h * NCHUNK + c) * 128 + m * 16 + lg * 4) * 128 + jf * 16 + lr;
#pragma unroll
    for (int r = 0; r < 4; ++r) out[r * 128] = (__bf16)S[r];
#pragma unroll
    for (int r = 0; r < 4; ++r) S[r] = df * S[r] + u[r];
  }
}

// ---- stage-3 attention + fused RMS-norm + gate ----
__global__ __launch_bounds__(256) void attn2_kernel(const __bf16* __restrict__ qb,
    const __bf16* __restrict__ kb, const __bf16* __restrict__ vtb,
    const __bf16* __restrict__ St, const __bf16* __restrict__ gateb,
    __bf16* __restrict__ ynormb) {
  __shared__ __bf16 kl[64 * 128];
  __shared__ __bf16 vl[128 * 64];
  __shared__ __bf16 pl[4][16 * 64];
  int h = blockIdx.x >> 5, qt = blockIdx.x & 31;
  int g = h >> 2;
  int w = threadIdx.x >> 6, l = threadIdx.x & 63;
  int lr = l & 15, lg = l >> 4;
  int t0b = qt * 64;
  int t0 = t0b + w * 16;
  bf16x8 qf[4];
#pragma unroll
  for (int kbk = 0; kbk < 4; ++kbk)
    qf[kbk] = *(const bf16x8*)(qb + ((size_t)h * T_SEQ + t0 + lr) * DH + kbk * 32 + lg * 8);
  float gamma = 1.0f - exp2f(-5.0f - (float)h);
  float l2g = log2f(gamma);
  const float scale = 0.088388347648318447f;  // 1/sqrt(128)
  int s0 = t0b;
#pragma unroll
  for (int it = 0; it < 4; ++it) {
    int fg = it * 256 + threadIdx.x;
    {
      int ss = fg >> 4, gr = fg & 15;
      bf16x8 kv = *(const bf16x8*)(kb + ((size_t)g * T_SEQ + s0 + ss) * DH + gr * 8);
      *(bf16x8*)((char*)kl + ss * 256 + ((gr * 16) ^ ((ss & 7) << 4))) = kv;
    }
    {
      int d = fg >> 3, gv = fg & 7;
      bf16x8 vv = *(const bf16x8*)(vtb + ((size_t)g * DH + d) * T_SEQ + s0 + gv * 8);
      *(bf16x8*)((char*)vl + d * 128 + ((gv * 16) ^ ((d & 7) << 4))) = vv;
    }
  }
  float wfac = scale * exp2f(l2g * (float)(w * 16 + lr));
  bf16x8 qwf[4];
#pragma unroll
  for (int kbk = 0; kbk < 4; ++kbk)
#pragma unroll
    for (int e = 0; e < 8; ++e) qwf[kbk][e] = (__bf16)((float)qf[kbk][e] * wfac);
  f32x4 acc[8] = {};
  const __bf16* Sb = St + (size_t)(h * NCHUNK + qt) * 16384;
#pragma unroll
  for (int dc = 0; dc < 8; ++dc)
#pragma unroll
    for (int kc = 0; kc < 4; ++kc) {
      bf16x8 sf = *(const bf16x8*)(Sb + (dc * 16 + lr) * 128 + kc * 32 + lg * 8);
      acc[dc] = __builtin_amdgcn_mfma_f32_16x16x32_bf16(qwf[kc], sf, acc[dc], 0, 0, 0);
    }
  __syncthreads();
#pragma unroll
  for (int sc = 0; sc < 4; ++sc) {
    f32x4 p = {0.f, 0.f, 0.f, 0.f};
    int srow = sc * 16 + lr;
#pragma unroll
    for (int kbk = 0; kbk < 4; ++kbk) {
      bf16x8 kf = *(const bf16x8*)((char*)kl + srow * 256 +
                                   ((kbk * 64 + lg * 16) ^ ((srow & 7) << 4)));
      p = __builtin_amdgcn_mfma_f32_16x16x32_bf16(qf[kbk], kf, p, 0, 0, 0);
    }
#pragma unroll
    for (int r = 0; r < 4; ++r) {
      int tl = lg * 4 + r;
      int diff = (w * 16 + tl) - srow;
      float val = 0.0f;
      if (diff >= 0) val = p[r] * scale * exp2f((float)diff * l2g);
      *(__bf16*)((char*)(pl[w]) + tl * 128 +
                 (((sc * 16 + lr) * 2) ^ ((tl & 7) << 4))) = (__bf16)val;
    }
  }
  bf16x8 pa[2];
#pragma unroll
  for (int kc = 0; kc < 2; ++kc)
    pa[kc] = *(const bf16x8*)((char*)(pl[w]) + lr * 128 +
                              ((kc * 64 + lg * 16) ^ ((lr & 7) << 4)));
#pragma unroll
  for (int dc = 0; dc < 8; ++dc) {
#pragma unroll
    for (int kc = 0; kc < 2; ++kc) {
      int vrow = dc * 16 + lr;
      bf16x8 vf = *(const bf16x8*)((char*)vl + vrow * 128 +
                                   ((kc * 64 + lg * 16) ^ ((vrow & 7) << 4)));
      acc[dc] = __builtin_amdgcn_mfma_f32_16x16x32_bf16(pa[kc], vf, acc[dc], 0, 0, 0);
    }
  }
  float rs[4];
#pragma unroll
  for (int r = 0; r < 4; ++r) {
    float ssum = 0.f;
#pragma unroll
    for (int dc = 0; dc < 8; ++dc) ssum += acc[dc][r] * acc[dc][r];
    ssum += __shfl_xor(ssum, 1, 64);
    ssum += __shfl_xor(ssum, 2, 64);
    ssum += __shfl_xor(ssum, 4, 64);
    ssum += __shfl_xor(ssum, 8, 64);
    rs[r] = rsqrtf(ssum * (1.0f / 128.0f) + 1e-5f);
  }
#pragma unroll
  for (int dc = 0; dc < 8; ++dc)
#pragma unroll
    for (int r = 0; r < 4; ++r) {
      size_t idx = (size_t)(t0 + lg * 4 + r) * CDIM + h * DH + dc * 16 + lr;
      float gv = (float)gateb[idx];
      ynormb[idx] = (__bf16)(acc[dc][r] * rs[r] * gv);
    }
}

// ------- GEMM: BMx128 tile (MI = BM/32 M-frags/wave), BK=64, depth-2 counted-vmcnt -------
// R14 verdict: MI=4 (128x128) regressed (occupancy loss: 64KB LDS -> 2 blocks/CU);
// MI=2 (64x128, 48KB LDS, ~3 blocks/CU) is the best of six structures tested. Use MI=2.
// MODE 0: Cf[row*N+col] = z (f32).
// MODE 1: fused epilogue -- n0<3072: RoPE q,k in-register and scatter to qb/kb/ktb, v->vtb;
//   n0>=3072: silu(z) -> gateb.
template<int MODE, int MI>
__global__ __launch_bounds__(256) void gemm_gl_kernel(
    const __bf16* __restrict__ A, const __bf16* __restrict__ Bt,
    float* __restrict__ Cf, __bf16* __restrict__ Cg,
    const float* __restrict__ cosb, const float* __restrict__ sinb,
    __bf16* __restrict__ qb, __bf16* __restrict__ kb,
    __bf16* __restrict__ vtb, __bf16* __restrict__ ktb,
    int M, int N, int K) {
  constexpr int BM = MI * 32;                    // 64 or 128
  __shared__ __bf16 Asb[2 * BM * 64];            // 2 x BM*128B buffers
  __shared__ __bf16 Bsb[2 * 128 * 64];           // 2 x 16KB buffers
  int m0 = blockIdx.x * BM, n0 = blockIdx.y * 128;
  int tid = threadIdx.x;
  int w = tid >> 6, l = tid & 63;
  int wr = w >> 1, wc = w & 1;                   // wave tile = (16*MI) x 64
  int lr = l & 15, lg = l >> 4;
  int nk = K >> 6;
  const __bf16* Ab = A + (size_t)m0 * K;
  const __bf16* Bb = Bt + (size_t)n0 * K;
  f32x4 acc[MI][4] = {};

  auto stage = [&](int buf, int k0) {
#pragma unroll
    for (int c = 0; c < MI; ++c) {
      int ca = c * 256 + tid, row = ca >> 3, ks = ca & 7;
      gl_lds16(Ab + (size_t)row * K + k0 + ((ks ^ (row & 7)) << 3),
               Asb + buf * (BM * 64) + ca * 8);
    }
#pragma unroll
    for (int c = 0; c < 4; ++c) {
      int cb2 = c * 256 + tid, row = cb2 >> 3, ks = cb2 & 7;
      gl_lds16(Bb + (size_t)row * K + k0 + ((ks ^ (row & 7)) << 3),
               Bsb + buf * 8192 + cb2 * 8);
    }
  };
  auto wait_tile = [] {                          // vmcnt(MI+4): one tile's loads outstanding
    if constexpr (MI == 2) asm volatile("s_waitcnt vmcnt(6)" ::: "memory");
    else                   asm volatile("s_waitcnt vmcnt(8)" ::: "memory");
  };

  // prologue: stage tiles 0 and 1; wait only for tile 0
  stage(0, 0);
  if (nk > 1) {
    stage(1, 64);
    wait_tile();
  } else {
    asm volatile("s_waitcnt vmcnt(0)" ::: "memory");
  }
  __builtin_amdgcn_s_barrier();

  int cur = 0;
  for (int kt = 0; kt < nk; ++kt) {
    const char* As = (const char*)(Asb + cur * (BM * 64));
    const char* Bs = (const char*)(Bsb + cur * 8192);
    bf16x8 av[MI][2], bv[4][2];
#pragma unroll
    for (int i = 0; i < MI; ++i)
#pragma unroll
      for (int kk = 0; kk < 2; ++kk) {
        int row = wr * (16 * MI) + i * 16 + lr;
        av[i][kk] = *(const bf16x8*)(As +
            ((row * 128 + kk * 64 + lg * 16) ^ ((lr & 7) << 4)));
      }
#pragma unroll
    for (int j = 0; j < 4; ++j)
#pragma unroll
      for (int kk = 0; kk < 2; ++kk) {
        int row = wc * 64 + j * 16 + lr;
        bv[j][kk] = *(const bf16x8*)(Bs +
            ((row * 128 + kk * 64 + lg * 16) ^ ((lr & 7) << 4)));
      }
#pragma unroll
    for (int kk = 0; kk < 2; ++kk)
#pragma unroll
      for (int i = 0; i < MI; ++i)
#pragma unroll
        for (int j = 0; j < 4; ++j)
          acc[i][j] = __builtin_amdgcn_mfma_f32_16x16x32_bf16(av[i][kk], bv[j][kk],
                                                              acc[i][j], 0, 0, 0);
    if (kt + 1 < nk) {
      __builtin_amdgcn_s_barrier();        // all waves finished reading buf cur
      if (kt + 2 < nk) {
        stage(cur, (kt + 2) << 6);         // refill buf cur; stays in flight next phase
        wait_tile();                       // tile kt+1 (oldest) landed
      } else {
        asm volatile("s_waitcnt vmcnt(0)" ::: "memory");   // tail: tile kt+1 landed
      }
      __builtin_amdgcn_s_barrier();
    }
    cur ^= 1;
  }

  if (MODE == 0) {
#pragma unroll
    for (int i = 0; i < MI; ++i) {
      int row = m0 + wr * (16 * MI) + i * 16 + lg * 4;
#pragma unroll
      for (int j = 0; j < 4; ++j) {
        int col = n0 + wc * 64 + j * 16 + lr;
#pragma unroll
        for (int r = 0; r < 4; ++r)
          Cf[(size_t)(row + r) * N + col] = acc[i][j][r];
      }
    }
    return;
  }
  // MODE 1 fused epilogue
  if (n0 >= 3072) {
#pragma unroll
    for (int i = 0; i < MI; ++i) {
      int row = m0 + wr * (16 * MI) + i * 16 + lg * 4;
#pragma unroll
      for (int j = 0; j < 4; ++j) {
        int col = n0 + wc * 64 + j * 16 + lr;
#pragma unroll
        for (int r = 0; r < 4; ++r) {
          float z = acc[i][j][r];
          float sv = z / (1.0f + expf(-z));
          Cg[(size_t)(row + r) * 2048 + (col - 3072)] = (__bf16)sv;
        }
      }
    }
    return;
  }
  // qkv section: rope q,k in-register and scatter; v -> vtb
#pragma unroll
  for (int i = 0; i < MI; ++i) {
    int row0 = m0 + wr * (16 * MI) + i * 16 + lg * 4;
#pragma unroll
    for (int j = 0; j < 4; ++j) {
      int cb = n0 + wc * 64 + j * 16;            // frag base col (wave-uniform)
      int g = cb / 768, cm = cb % 768;
      int dbase = (cm < 512) ? (cm & 127) : (cm < 640) ? (cm - 512) : (cm - 640);
      int d = dbase + lr;
      float ov[4];
      if (cm < 640) {                            // rope (q or k)
#pragma unroll
        for (int r = 0; r < 4; ++r) {
          float z = acc[i][j][r];
          float pz = __shfl_xor(z, 1, 64);       // pair partner (col parity == lr parity)
          int t = row0 + r;
          float cc = cosb[t * 64 + (d >> 1)];
          float ss = sinb[t * 64 + (d >> 1)];
          ov[r] = (lr & 1) ? (pz * ss + z * cc) : (z * cc - pz * ss);
        }
      } else {
#pragma unroll
        for (int r = 0; r < 4; ++r) ov[r] = acc[i][j][r];
      }
      if (cm < 512) {                            // q -> qb[h][t][d]
        int hh = g * 4 + (cm >> 7);
#pragma unroll
        for (int r = 0; r < 4; ++r)
          qb[((size_t)hh * T_SEQ + row0 + r) * DH + d] = (__bf16)ov[r];
      } else if (cm < 640) {                     // k -> kb[g][t][d] and ktb[g][d][t]
        bf16x4 kv;
#pragma unroll
        for (int r = 0; r < 4; ++r) {
          kv[r] = (__bf16)ov[r];
          kb[((size_t)g * T_SEQ + row0 + r) * DH + d] = kv[r];
        }
        *(bf16x4*)(ktb + ((size_t)g * DH + d) * T_SEQ + row0) = kv;
      } else {                                   // v -> vtb[g][d][t]
        bf16x4 vv;
#pragma unroll
        for (int r = 0; r < 4; ++r) vv[r] = (__bf16)ov[r];
        *(bf16x4*)(vtb + ((size_t)g * DH + d) * T_SEQ + row0) = vv;
      }
    }
  }
}

extern "C" void kernel_launch(void* const* d_in, const int* in_sizes, int n_in,
                              void* d_out, int out_size, void* d_ws, size_t ws_size,
                              hipStream_t stream) {
  const float* x    = (const float*)d_in[0];
  const float* cosb = (const float*)d_in[1];
  const float* sinb = (const float*)d_in[2];
  // d_in[3] = mask (268MB) -- computed analytically, never read
  const float* Wr   = (const float*)d_in[4];
  const float* Wg   = (const float*)d_in[5];
  const float* Wp   = (const float*)d_in[6];

  char* ws = (char*)d_ws;
  size_t off = 0;
  auto alloc = [&](size_t bytes) { void* p = ws + off; off += (bytes + 255) & ~(size_t)255; return p; };
  __bf16* xb     = (__bf16*)alloc((size_t)CDIM * CDIM * 2);          // 8MB
  __bf16* wtb    = (__bf16*)alloc((size_t)5120 * CDIM * 2);          // 20MB (W_reten^T|W_gate^T)
  __bf16* wpb    = (__bf16*)alloc((size_t)CDIM * CDIM * 2);          // 8MB
  __bf16* qb     = (__bf16*)alloc((size_t)NH * T_SEQ * DH * 2);      // 8MB
  __bf16* kbp    = (__bf16*)alloc((size_t)NG * T_SEQ * DH * 2);      // 2MB
  __bf16* vtb    = (__bf16*)alloc((size_t)NG * DH * T_SEQ * 2);      // 2MB
  __bf16* ktb    = (__bf16*)alloc((size_t)NG * DH * T_SEQ * 2);      // 2MB
  __bf16* gateb  = (__bf16*)alloc((size_t)CDIM * CDIM * 2);          // 8MB
  __bf16* Stb    = (__bf16*)alloc((size_t)NH * NCHUNK * 128 * 128 * 2); // 16MB
  __bf16* ynormb = (__bf16*)alloc((size_t)T_SEQ * CDIM * 2);         // 8MB

  // 1) preprocess: cast x + transpose/cast all weights
  pre_kernel<<<5632, 256, 0, stream>>>(x, Wr, Wg, Wp, xb, wtb, wpb);
  // 2) fused: x @ [W_reten | W_gate] with in-epilogue RoPE/scatter/transpose + silu gate
  //    64x128 tile (MI=2): best measured of six structures (R10: 155us total).
  gemm_gl_kernel<1, 2><<<dim3(32, 40), 256, 0, stream>>>(
      xb, wtb, nullptr, gateb, cosb, sinb, qb, kbp, vtb, ktb, 2048, 5120, 2048);
  // 3) fused per-chunk decayed KV outer products + state scan -> St bf16
  uscan_kernel<<<256, 256, 0, stream>>>(vtb, ktb, Stb);
  // 4) attention (intra tile + q@S_c) + fused RMS-norm + gate -> ynorm bf16 [T][C]
  attn2_kernel<<<NH * NCHUNK, 256, 0, stream>>>(qb, kbp, vtb, Stb, gateb, ynormb);
  // 5) out = (g*y_norm) @ W_proj -- 64x128 (MI=2), 512 blocks = 2/CU (proven R10 config)
  gemm_gl_kernel<0, 2><<<dim3(32, 16), 256, 0, stream>>>(
      ynormb, wpb, (float*)d_out, nullptr, nullptr, nullptr, nullptr, nullptr, nullptr, nullptr,
      2048, 2048, 2048);
}